// Round 5
// baseline (216.283 us; speedup 1.0000x reference)
//
#include <hip/hip_runtime.h>
#include <hip/hip_bf16.h>

typedef __attribute__((ext_vector_type(8))) short short8;
typedef __attribute__((ext_vector_type(4))) float f32x4;

#define HWPIX 147456   // 384*384
#define NC 64
#define NO 64
#define NM 4
#define EPSV 1e-5f

// hand round-to-nearest-even f32->bf16 (proven: R1/R2/R4; do NOT use (__bf16) casts)
static __device__ __forceinline__ unsigned short f2bf(float f) {
    unsigned int u = __float_as_uint(f);
    u += 0x7fffu + ((u >> 16) & 1u);
    return (unsigned short)(u >> 16);
}
static __device__ __forceinline__ float bf2f(unsigned short h) {
    return __uint_as_float(((unsigned int)h) << 16);
}

// Fused LayerNorm -> 4x(1x1 conv) -> sum_m relu(z-q), zero LDS, zero barriers.
// Block = 64-pixel strip, 4 waves; wave wv owns o-slice [wv*16, wv*16+16).
// Each wave redundantly LayerNorms the strip's 64 pixels with a FRAG-ALIGNED
// channel->lane mapping: lane (g4,p16) holds channels {g4*8+j, 32+g4*8+j},
// which IS its MFMA A-fragment -> no cross-lane exchange after the LN reduce.
// Numerics: x in bf16-hi only; W split hi+lo (2-term: xh*Wh + xh*Wl).
__global__ __launch_bounds__(256) void dnm_fused(
    const float* __restrict__ x, const float* __restrict__ Wg,
    const float* __restrict__ qp, const float* __restrict__ gamma,
    const float* __restrict__ beta, float* __restrict__ out)
{
    const int tid = threadIdx.x;
    const int wv  = tid >> 6;        // wave id = o-slice
    const int ln  = tid & 63;
    const int p16 = ln & 15;         // o-local (B-row) AND pixel-column for loads
    const int g4  = ln >> 4;         // k-chunk group 0..3

    const int bid = blockIdx.x;      // 9216 blocks = 4 batches * 2304 strips
    const int b   = bid / 2304;
    const int P0  = (bid % 2304) * 64;

    const float qv = qp[0];

    // ---- W' = gamma .* W split hi/lo; bias[m] = sum_c beta_c * W'[m][o][c].
    // lane (g4,p16): o = wv*16+p16, channels c = ch*32 + g4*8 + j  (j=0..7)
    short8 wh[NM][2], wl[NM][2];
    float bias[NM];
    {
        f32x4 gA[2], gB[2], bA[2], bB[2];
#pragma unroll
        for (int ch = 0; ch < 2; ++ch) {
            gA[ch] = *(const f32x4*)(gamma + ch * 32 + g4 * 8);
            gB[ch] = *(const f32x4*)(gamma + ch * 32 + g4 * 8 + 4);
            bA[ch] = *(const f32x4*)(beta  + ch * 32 + g4 * 8);
            bB[ch] = *(const f32x4*)(beta  + ch * 32 + g4 * 8 + 4);
        }
#pragma unroll
        for (int m = 0; m < NM; ++m) {
            float bsum = 0.f;
#pragma unroll
            for (int ch = 0; ch < 2; ++ch) {
                const float* wp = Wg + ((m * NO + (wv * 16 + p16)) * NC + ch * 32 + g4 * 8);
                f32x4 a = *(const f32x4*)(wp);
                f32x4 c = *(const f32x4*)(wp + 4);
                float f[8]  = {a[0], a[1], a[2], a[3], c[0], c[1], c[2], c[3]};
                float gg[8] = {gA[ch][0], gA[ch][1], gA[ch][2], gA[ch][3],
                               gB[ch][0], gB[ch][1], gB[ch][2], gB[ch][3]};
                float bb[8] = {bA[ch][0], bA[ch][1], bA[ch][2], bA[ch][3],
                               bB[ch][0], bB[ch][1], bB[ch][2], bB[ch][3]};
#pragma unroll
                for (int j = 0; j < 8; ++j) {
                    bsum += bb[j] * f[j];
                    float wq = gg[j] * f[j];
                    unsigned short h  = f2bf(wq);
                    unsigned short lo = f2bf(wq - bf2f(h));
                    wh[m][ch][j] = (short)h;
                    wl[m][ch][j] = (short)lo;
                }
            }
            bsum += __shfl_xor(bsum, 16);
            bsum += __shfl_xor(bsum, 32);   // full sum over c for this o
            bias[m] = bsum;
        }
    }

    // x base for this lane's channel groups: group0 c = g4*8+j, group1 c = 32+g4*8+j
    const float* xp = x + (size_t)b * NC * HWPIX + (size_t)(g4 * 8) * HWPIX + P0 + p16;
    float* const outw = out + (size_t)b * NO * HWPIX
                            + (size_t)(wv * 16 + p16) * HWPIX + P0;

#pragma unroll 1
    for (int ps = 0; ps < 4; ++ps) {
        const float* xq = xp + ps * 16;     // this subtile's pixel column p16

        // ---- load 16 channels of pixel (P0+ps*16+p16) — the frag channels
        float xv[16];
#pragma unroll
        for (int j = 0; j < 8; ++j) {
            xv[j]     = xq[(size_t)j * HWPIX];
            xv[8 + j] = xq[(size_t)(32 + j) * HWPIX];
        }

        // ---- LayerNorm: in-lane partial sums + 4-lane (stride-16) reduce
        float s1 = 0.f, s2 = 0.f;
#pragma unroll
        for (int i = 0; i < 16; ++i) { s1 += xv[i]; s2 += xv[i] * xv[i]; }
        s1 += __shfl_xor(s1, 16);  s2 += __shfl_xor(s2, 16);
        s1 += __shfl_xor(s1, 32);  s2 += __shfl_xor(s2, 32);
        const float mu  = s1 * (1.f / 64.f);
        const float var = s2 * (1.f / 64.f) - mu * mu;   // biased (torch)
        const float rs  = rsqrtf(var + EPSV);

        // ---- xn -> bf16 A-fragments, already in-lane (frag-aligned mapping)
        short8 fh[2];
#pragma unroll
        for (int j = 0; j < 8; ++j) {
            fh[0][j] = (short)f2bf((xv[j]     - mu) * rs);
            fh[1][j] = (short)f2bf((xv[8 + j] - mu) * rs);
        }

        // ---- MFMA, 2-term: xh*Wh + xh*Wl
        f32x4 acc[NM];
#pragma unroll
        for (int m = 0; m < NM; ++m) {
            f32x4 a = {bias[m], bias[m], bias[m], bias[m]};
#pragma unroll
            for (int ch = 0; ch < 2; ++ch) {
                a = __builtin_amdgcn_mfma_f32_16x16x32_bf16(fh[ch], wh[m][ch], a, 0, 0, 0);
                a = __builtin_amdgcn_mfma_f32_16x16x32_bf16(fh[ch], wl[m][ch], a, 0, 0, 0);
            }
            acc[m] = a;
        }

        // ---- fold m + store; D: col(p16)=o-local, row(g4*4+rr)=pixel-local
        f32x4 v;
#pragma unroll
        for (int rr = 0; rr < 4; ++rr) {
            v[rr] = fmaxf(acc[0][rr] - qv, 0.f) + fmaxf(acc[1][rr] - qv, 0.f)
                  + fmaxf(acc[2][rr] - qv, 0.f) + fmaxf(acc[3][rr] - qv, 0.f);
        }
        *(f32x4*)(outw + ps * 16 + g4 * 4) = v;   // 4 consecutive pixels
    }
}

extern "C" void kernel_launch(void* const* d_in, const int* in_sizes, int n_in,
                              void* d_out, int out_size, void* d_ws, size_t ws_size,
                              hipStream_t stream) {
    const float* x     = (const float*)d_in[0];
    const float* Wg    = (const float*)d_in[1];
    const float* q     = (const float*)d_in[2];
    const float* gamma = (const float*)d_in[3];
    const float* beta  = (const float*)d_in[4];
    float* out = (float*)d_out;

    // 4 batches * 2304 strips of 64 pixels; 4 independent waves per block
    dnm_fused<<<dim3(9216), dim3(256), 0, stream>>>(x, Wg, q, gamma, beta, out);
}

// Round 8
// 83.879 us; speedup vs baseline: 2.5785x; 2.5785x over previous
//
#include <hip/hip_runtime.h>
#include <hip/hip_bf16.h>

typedef __attribute__((ext_vector_type(8))) short short8;
typedef __attribute__((ext_vector_type(4))) float f32x4;

#define HWPIX 147456   // 384*384
#define NC 64
#define NO 64
#define NM 4
#define EPSV 1e-5f

// hand round-to-nearest-even f32->bf16 (proven R1-R5; never use (__bf16) casts)
static __device__ __forceinline__ unsigned short f2bf(float f) {
    unsigned int u = __float_as_uint(f);
    u += 0x7fffu + ((u >> 16) & 1u);
    return (unsigned short)(u >> 16);
}
static __device__ __forceinline__ float bf2f(unsigned short h) {
    return __uint_as_float(((unsigned int)h) << 16);
}

// raw barrier: LDS-visibility only, keeps global loads in flight (T4)
#define BAR() do { asm volatile("s_waitcnt lgkmcnt(0)" ::: "memory"); \
                   __builtin_amdgcn_s_barrier();                      \
                   asm volatile("" ::: "memory"); } while (0)

// R2 skeleton (proven): LayerNorm -> stacked 1x1 conv -> sum_m relu(z-q).
// A = xn-hi (LDS dbuf, XOR-swizzled), B = gamma*W split hi/lo (regs),
// beta folded into acc init.  2-term split: xh*Wh + xh*Wl (R5-proven).
// Epilogue: sum_m max(z,q) - 4q (R4-proven).  1-deep prefetch, 1 barrier/iter.
__global__ __launch_bounds__(256) void dnm_fused(
    const float* __restrict__ x, const float* __restrict__ Wg,
    const float* __restrict__ qp, const float* __restrict__ gamma,
    const float* __restrict__ beta, float* __restrict__ out)
{
    // per buffer: xn-hi only. Row = pixel (64 rows x 128B of bf16[64]),
    // 16B slots swizzled: byte = r*128 + ((slot ^ (r&7))<<4)
    __shared__ __align__(16) unsigned char lds[2][8192];

    const int tid = threadIdx.x;
    const int wv  = tid >> 6;        // wave 0..3 (owns o-slice wv*16..+16)
    const int ln  = tid & 63;
    const int p16 = ln & 15;
    const int g4  = ln >> 4;         // k-chunk group 0..3

    const int bid = blockIdx.x;      // 2304 blocks: 576 per batch image
    const int b       = bid / 576;
    const int pixbase = (bid % 576) * 256;

    const float qv = qp[0];
    const float q4 = 4.0f * qv;

    // ---- B operand: W' = gamma .* W split hi/lo; bias[m] = sum_c beta_c*W[m][o][c]
    // lane holds row o = wv*16+p16, k = ch*32 + g4*8 + j
    f32x4 gA[2], gB[2], bA[2], bB[2];
#pragma unroll
    for (int ch = 0; ch < 2; ++ch) {
        gA[ch] = *(const f32x4*)(gamma + ch * 32 + g4 * 8);
        gB[ch] = *(const f32x4*)(gamma + ch * 32 + g4 * 8 + 4);
        bA[ch] = *(const f32x4*)(beta  + ch * 32 + g4 * 8);
        bB[ch] = *(const f32x4*)(beta  + ch * 32 + g4 * 8 + 4);
    }
    short8 wh[NM][2], wl[NM][2];
    float bias[NM];
#pragma unroll
    for (int m = 0; m < NM; ++m) {
        float bsum = 0.f;
#pragma unroll
        for (int ch = 0; ch < 2; ++ch) {
            const float* wp = Wg + ((m * NO + (wv * 16 + p16)) * NC + ch * 32 + g4 * 8);
            f32x4 a = *(const f32x4*)(wp);
            f32x4 c = *(const f32x4*)(wp + 4);
            float f[8]  = {a[0], a[1], a[2], a[3], c[0], c[1], c[2], c[3]};
            float gg[8] = {gA[ch][0], gA[ch][1], gA[ch][2], gA[ch][3],
                           gB[ch][0], gB[ch][1], gB[ch][2], gB[ch][3]};
            float bb[8] = {bA[ch][0], bA[ch][1], bA[ch][2], bA[ch][3],
                           bB[ch][0], bB[ch][1], bB[ch][2], bB[ch][3]};
#pragma unroll
            for (int j = 0; j < 8; ++j) {
                bsum += bb[j] * f[j];
                float wq = gg[j] * f[j];
                unsigned short h  = f2bf(wq);
                unsigned short lo = f2bf(wq - bf2f(h));
                wh[m][ch][j] = (short)h;
                wl[m][ch][j] = (short)lo;
            }
        }
        bsum += __shfl_xor(bsum, 16);
        bsum += __shfl_xor(bsum, 32);   // full sum over c for this o
        bias[m] = bsum;
    }

    const float* xpl = x + (size_t)b * NC * HWPIX + pixbase + wv * 16 + p16
                         + (size_t)(g4 * 16) * HWPIX;
    float* const outw = out + (size_t)b * NO * HWPIX
                            + (size_t)(wv * 16 + p16) * HWPIX + pixbase;

    const int r  = wv * 16 + p16;    // LDS row this lane writes
    const int rk = r & 7;

    // prologue: loads for it=0
    float xv[16];
#pragma unroll
    for (int i = 0; i < 16; ++i) xv[i] = xpl[(size_t)i * HWPIX];

#pragma unroll 1
    for (int it = 0; it < 4; ++it) {
        unsigned char* buf = lds[it & 1];

        // ---- LN on prefetched xv (this wave's 16-px subtile, once per pixel)
        {
            float s1 = 0.f, s2 = 0.f;
#pragma unroll
            for (int i = 0; i < 16; ++i) { s1 += xv[i]; s2 += xv[i] * xv[i]; }
            s1 += __shfl_xor(s1, 16);  s2 += __shfl_xor(s2, 16);
            s1 += __shfl_xor(s1, 32);  s2 += __shfl_xor(s2, 32);
            const float mu  = s1 * (1.f / 64.f);
            const float var = s2 * (1.f / 64.f) - mu * mu;   // biased (torch)
            const float rs  = rsqrtf(var + EPSV);
            short8 hi0, hi1;
#pragma unroll
            for (int i = 0; i < 16; ++i) {
                float xn = (xv[i] - mu) * rs;   // gamma/beta folded into W/bias
                unsigned short h = f2bf(xn);
                if (i < 8) hi0[i] = (short)h; else hi1[i - 8] = (short)h;
            }
            const int s0 = g4 * 2;
            *(short8*)(buf + r * 128 + (((s0    ) ^ rk) << 4)) = hi0;
            *(short8*)(buf + r * 128 + (((s0 + 1) ^ rk) << 4)) = hi1;
        }
        BAR();

        // ---- prefetch next tile's x (in flight across the MFMA phase)
        if (it < 3) {
            const float* xp = xpl + (it + 1) * 64;
#pragma unroll
            for (int i = 0; i < 16; ++i) xv[i] = xp[(size_t)i * HWPIX];
        }

        // ---- MFMA: wave covers its o-slice for all 4 pixel-subtiles
#pragma unroll 1
        for (int ps = 0; ps < 4; ++ps) {
            const int row = ps * 16 + p16;
            const int rwk = row & 7;
            short8 ah[2];
#pragma unroll
            for (int ch = 0; ch < 2; ++ch) {
                const int slot = ch * 4 + g4;
                ah[ch] = *(const short8*)(buf + row * 128 + ((slot ^ rwk) << 4));
            }
            f32x4 acc[NM];
#pragma unroll
            for (int m = 0; m < NM; ++m) {
                f32x4 a = {bias[m], bias[m], bias[m], bias[m]};
#pragma unroll
                for (int ch = 0; ch < 2; ++ch) {
                    // 2-term split: xh*Wh + xh*Wl (R5-proven numerics)
                    a = __builtin_amdgcn_mfma_f32_16x16x32_bf16(ah[ch], wh[m][ch], a, 0, 0, 0);
                    a = __builtin_amdgcn_mfma_f32_16x16x32_bf16(ah[ch], wl[m][ch], a, 0, 0, 0);
                }
                acc[m] = a;
            }
            // sum_m relu(z-q) = sum_m max(z,q) - 4q (R4-proven);
            // D: col(p16)=o-local, row(g4*4+rr)=pixel-local
            f32x4 v;
#pragma unroll
            for (int rr = 0; rr < 4; ++rr) {
                v[rr] = (fmaxf(acc[0][rr], qv) + fmaxf(acc[1][rr], qv))
                      + (fmaxf(acc[2][rr], qv) + fmaxf(acc[3][rr], qv)) - q4;
            }
            *(f32x4*)(outw + it * 64 + ps * 16 + g4 * 4) = v;   // 4 consecutive px
        }
        // single barrier per iter: buffer b reused at it+2 is ordered by
        // BAR(it+1), which every wave reaches only after its it-phase reads.
    }
}

extern "C" void kernel_launch(void* const* d_in, const int* in_sizes, int n_in,
                              void* d_out, int out_size, void* d_ws, size_t ws_size,
                              hipStream_t stream) {
    const float* x     = (const float*)d_in[0];
    const float* Wg    = (const float*)d_in[1];
    const float* q     = (const float*)d_in[2];
    const float* gamma = (const float*)d_in[3];
    const float* beta  = (const float*)d_in[4];
    float* out = (float*)d_out;

    dnm_fused<<<dim3(2304), dim3(256), 0, stream>>>(x, Wg, q, gamma, beta, out);
}

// Round 9
// 75.737 us; speedup vs baseline: 2.8557x; 1.1075x over previous
//
#include <hip/hip_runtime.h>
#include <hip/hip_bf16.h>

typedef __attribute__((ext_vector_type(8))) short short8;
typedef __attribute__((ext_vector_type(4))) float f32x4;
typedef __attribute__((ext_vector_type(4))) unsigned int u32x4;

#define HWPIX 147456   // 384*384
#define NC 64
#define NO 64
#define NM 4
#define EPSV 1e-5f

// f32 pair -> packed bf16x2, round-to-nearest-even (hardware instruction).
// bits[15:0] = bf16(a), bits[31:16] = bf16(b).
static __device__ __forceinline__ unsigned int cvt_pk(float a, float b) {
    unsigned int r;
    asm("v_cvt_pk_bf16_f32 %0, %1, %2" : "=v"(r) : "v"(a), "v"(b));
    return r;
}
static __device__ __forceinline__ float asf(unsigned int u) {
    return __uint_as_float(u);
}

// raw barrier: LDS-visibility only, keeps global loads in flight (T4)
#define BAR() do { asm volatile("s_waitcnt lgkmcnt(0)" ::: "memory"); \
                   __builtin_amdgcn_s_barrier();                      \
                   asm volatile("" ::: "memory"); } while (0)

// R8-proven skeleton: LayerNorm -> stacked 1x1 conv -> sum_m relu(z-q).
// A = xn-hi (LDS dbuf, XOR-swizzled), B = gamma*W split hi/lo (regs),
// beta folded into acc init.  2-term split: xh*Wh + xh*Wl.
// Epilogue: sum_m max(z,q) - 4q.  1-deep prefetch, 1 raw barrier/iter.
// R9: v_cvt_pk_bf16_f32 converts; 512 px/block (8 iters) amortizes prologue.
__global__ __launch_bounds__(256) void dnm_fused(
    const float* __restrict__ x, const float* __restrict__ Wg,
    const float* __restrict__ qp, const float* __restrict__ gamma,
    const float* __restrict__ beta, float* __restrict__ out)
{
    // per buffer: xn-hi. Row = pixel (64 rows x 128B of bf16[64]),
    // 16B slots swizzled: byte = r*128 + ((slot ^ (r&7))<<4)
    __shared__ __align__(16) unsigned char lds[2][8192];

    const int tid = threadIdx.x;
    const int wv  = tid >> 6;        // wave 0..3 (owns o-slice wv*16..+16)
    const int ln  = tid & 63;
    const int p16 = ln & 15;
    const int g4  = ln >> 4;         // k-chunk group 0..3

    const int bid = blockIdx.x;      // 1152 blocks: 288 strips of 512 px per image
    const int b       = bid / 288;
    const int pixbase = (bid % 288) * 512;

    const float qv = qp[0];
    const float q4 = 4.0f * qv;

    // ---- B operand: W' = gamma .* W split hi/lo; bias[m] = sum_c beta_c*W[m][o][c]
    // lane holds row o = wv*16+p16, k = ch*32 + g4*8 + j
    f32x4 gA[2], gB[2], bA[2], bB[2];
#pragma unroll
    for (int ch = 0; ch < 2; ++ch) {
        gA[ch] = *(const f32x4*)(gamma + ch * 32 + g4 * 8);
        gB[ch] = *(const f32x4*)(gamma + ch * 32 + g4 * 8 + 4);
        bA[ch] = *(const f32x4*)(beta  + ch * 32 + g4 * 8);
        bB[ch] = *(const f32x4*)(beta  + ch * 32 + g4 * 8 + 4);
    }
    short8 wh[NM][2], wl[NM][2];
    float bias[NM];
#pragma unroll
    for (int m = 0; m < NM; ++m) {
        float bsum = 0.f;
#pragma unroll
        for (int ch = 0; ch < 2; ++ch) {
            const float* wp = Wg + ((m * NO + (wv * 16 + p16)) * NC + ch * 32 + g4 * 8);
            f32x4 a = *(const f32x4*)(wp);
            f32x4 c = *(const f32x4*)(wp + 4);
            float f[8]  = {a[0], a[1], a[2], a[3], c[0], c[1], c[2], c[3]};
            float gg[8] = {gA[ch][0], gA[ch][1], gA[ch][2], gA[ch][3],
                           gB[ch][0], gB[ch][1], gB[ch][2], gB[ch][3]};
            float bb[8] = {bA[ch][0], bA[ch][1], bA[ch][2], bA[ch][3],
                           bB[ch][0], bB[ch][1], bB[ch][2], bB[ch][3]};
            float wq[8];
#pragma unroll
            for (int j = 0; j < 8; ++j) {
                bsum += bb[j] * f[j];
                wq[j] = gg[j] * f[j];
            }
            u32x4 hu, lu;
#pragma unroll
            for (int p = 0; p < 4; ++p) {
                unsigned int h = cvt_pk(wq[2*p], wq[2*p+1]);
                float r0 = wq[2*p]   - asf(h << 16);          // bf2f(hi.lo) free
                float r1 = wq[2*p+1] - asf(h & 0xffff0000u);  // bf2f(hi.hi) free
                hu[p] = h;
                lu[p] = cvt_pk(r0, r1);
            }
            wh[m][ch] = __builtin_bit_cast(short8, hu);
            wl[m][ch] = __builtin_bit_cast(short8, lu);
        }
        bsum += __shfl_xor(bsum, 16);
        bsum += __shfl_xor(bsum, 32);   // full sum over c for this o
        bias[m] = bsum;
    }

    const float* xpl = x + (size_t)b * NC * HWPIX + pixbase + wv * 16 + p16
                         + (size_t)(g4 * 16) * HWPIX;
    float* const outw = out + (size_t)b * NO * HWPIX
                            + (size_t)(wv * 16 + p16) * HWPIX + pixbase;

    const int r  = wv * 16 + p16;    // LDS row this lane writes
    const int rk = r & 7;

    // prologue: loads for it=0
    float xv[16];
#pragma unroll
    for (int i = 0; i < 16; ++i) xv[i] = xpl[(size_t)i * HWPIX];

#pragma unroll 1
    for (int it = 0; it < 8; ++it) {
        unsigned char* buf = lds[it & 1];

        // ---- LN on prefetched xv (this wave's 16-px subtile, once per pixel)
        {
            float s1 = 0.f, s2 = 0.f;
#pragma unroll
            for (int i = 0; i < 16; ++i) { s1 += xv[i]; s2 += xv[i] * xv[i]; }
            s1 += __shfl_xor(s1, 16);  s2 += __shfl_xor(s2, 16);
            s1 += __shfl_xor(s1, 32);  s2 += __shfl_xor(s2, 32);
            const float mu  = s1 * (1.f / 64.f);
            const float var = s2 * (1.f / 64.f) - mu * mu;   // biased (torch)
            const float rs  = rsqrtf(var + EPSV);
            u32x4 h0, h1;
#pragma unroll
            for (int p = 0; p < 4; ++p) {
                h0[p] = cvt_pk((xv[2*p]     - mu) * rs, (xv[2*p+1] - mu) * rs);
                h1[p] = cvt_pk((xv[8+2*p]   - mu) * rs, (xv[9+2*p] - mu) * rs);
            }
            const int s0 = g4 * 2;
            *(u32x4*)(buf + r * 128 + (((s0    ) ^ rk) << 4)) = h0;
            *(u32x4*)(buf + r * 128 + (((s0 + 1) ^ rk) << 4)) = h1;
        }
        BAR();

        // ---- prefetch next tile's x (in flight across the MFMA phase)
        if (it < 7) {
            const float* xp = xpl + (it + 1) * 64;
#pragma unroll
            for (int i = 0; i < 16; ++i) xv[i] = xp[(size_t)i * HWPIX];
        }

        // ---- MFMA: wave covers its o-slice for all 4 pixel-subtiles
#pragma unroll 1
        for (int ps = 0; ps < 4; ++ps) {
            const int row = ps * 16 + p16;
            const int rwk = row & 7;
            short8 ah[2];
#pragma unroll
            for (int ch = 0; ch < 2; ++ch) {
                const int slot = ch * 4 + g4;
                ah[ch] = *(const short8*)(buf + row * 128 + ((slot ^ rwk) << 4));
            }
            f32x4 acc[NM];
#pragma unroll
            for (int m = 0; m < NM; ++m) {
                f32x4 a = {bias[m], bias[m], bias[m], bias[m]};
#pragma unroll
                for (int ch = 0; ch < 2; ++ch) {
                    // 2-term split: xh*Wh + xh*Wl (R5/R8-proven numerics)
                    a = __builtin_amdgcn_mfma_f32_16x16x32_bf16(ah[ch], wh[m][ch], a, 0, 0, 0);
                    a = __builtin_amdgcn_mfma_f32_16x16x32_bf16(ah[ch], wl[m][ch], a, 0, 0, 0);
                }
                acc[m] = a;
            }
            // sum_m relu(z-q) = sum_m max(z,q) - 4q (R4-proven);
            // D: col(p16)=o-local, row(g4*4+rr)=pixel-local
            f32x4 v;
#pragma unroll
            for (int rr = 0; rr < 4; ++rr) {
                v[rr] = (fmaxf(acc[0][rr], qv) + fmaxf(acc[1][rr], qv))
                      + (fmaxf(acc[2][rr], qv) + fmaxf(acc[3][rr], qv)) - q4;
            }
            *(f32x4*)(outw + it * 64 + ps * 16 + g4 * 4) = v;   // 4 consecutive px
        }
        // single barrier per iter: buffer b reused at it+2 is ordered by
        // BAR(it+1), which every wave reaches only after its it-phase reads.
    }
}

extern "C" void kernel_launch(void* const* d_in, const int* in_sizes, int n_in,
                              void* d_out, int out_size, void* d_ws, size_t ws_size,
                              hipStream_t stream) {
    const float* x     = (const float*)d_in[0];
    const float* Wg    = (const float*)d_in[1];
    const float* q     = (const float*)d_in[2];
    const float* gamma = (const float*)d_in[3];
    const float* beta  = (const float*)d_in[4];
    float* out = (float*)d_out;

    // 4 images * 288 strips of 512 px = 1152 blocks
    dnm_fused<<<dim3(1152), dim3(256), 0, stream>>>(x, Wg, q, gamma, beta, out);
}